// Round 8
// baseline (207.169 us; speedup 1.0000x reference)
//
#include <hip/hip_runtime.h>

#define NN 10000
#define EE_ 80000
#define NODE_ROWS 20000
#define NODE_BLOCKS 79         // ceil(20000/256)
#define EDGE_BLOCKS 625        // 160000/256 exact

// Clang builtin vector: volatile loads are legal (unlike HIP_vector_type float4)
// and still emit global_load_dwordx4.
typedef float f4 __attribute__((ext_vector_type(4)));

// ---------------------------------------------------------------------------
// chain_kernel: 32 blocks x 64 threads (1 wave). Block (c,q) evolves column q
// of chain c's 64x16 suffix product right-to-left:
//   v_64 = Wout[:,q];  v_i = Whid[i] @ v_{i+1};  beta += bhid[i].v_{i+1}
// Weights prefetched 2 layers deep into 4 rotating register buffers.
// volatile loads: pinned at issue (cannot be IR-sunk to use — R5 failure mode),
// yet compiler-tracked -> automatic counted vmcnt before first use (2 steps later).
// ws: [0..512) node W_eff 32x16, [512..640) edge 8x16.
// ---------------------------------------------------------------------------
__global__ __launch_bounds__(64, 1) void chain_kernel(
    const float* __restrict__ nWin, const float* __restrict__ nbin,
    const float* __restrict__ nWhid, const float* __restrict__ nbhid,
    const float* __restrict__ nWout, const float* __restrict__ nbout,
    const float* __restrict__ eWin, const float* __restrict__ ebin,
    const float* __restrict__ eWhid, const float* __restrict__ ebhid,
    const float* __restrict__ eWout, const float* __restrict__ ebout,
    float* __restrict__ ws)
{
  const int lane = threadIdx.x;          // 0..63 = vector row k
  const int c = blockIdx.x >> 4;         // 0 node, 1 edge
  const int q = blockIdx.x & 15;         // output column
  const float* Win  = c ? eWin  : nWin;
  const float* bin  = c ? ebin  : nbin;
  const float* Whid = c ? eWhid : nWhid;
  const float* bhid = c ? ebhid : nbhid;
  const float* Wout = c ? eWout : nWout;
  const float* bout = c ? ebout : nbout;
  const int din = c ? 7 : 31;
  float* weff = ws + (c ? 512 : 0);

  __shared__ float s_v[64];

  const float* Wr = Whid + (size_t)lane*64;   // this lane's row base
  const float* Br = bhid + lane;

  float v = Wout[lane*16 + q];                // v_64[lane]
  float bpart = 0.f;

  f4 w0[16], w1[16], w2[16], w3[16];
  float b0, b1, b2, b3;

  // prologue: prime w0 = layer 63, w1 = layer 62 (volatile: pinned here)
  {
    const volatile f4* p63 = (const volatile f4*)(Wr + (size_t)63*4096);
    #pragma unroll
    for (int kb = 0; kb < 16; ++kb) w0[kb] = p63[kb];
    b0 = *(const volatile float*)(Br + 63*64);
    const volatile f4* p62 = (const volatile f4*)(Wr + (size_t)62*4096);
    #pragma unroll
    for (int kb = 0; kb < 16; ++kb) w1[kb] = p62[kb];
    b1 = *(const volatile float*)(Br + 62*64);
  }

  // one chain step: apply (WU,BU); prefetch layer LPX into (WP,BP)
#define CSTEP(WU, BU, WP, BP, LPX) do {                                        \
    s_v[lane] = v;                                                             \
    { int lp_ = (LPX); lp_ = lp_ < 0 ? 0 : lp_;                                \
      const volatile f4* pw_ = (const volatile f4*)(Wr + (size_t)lp_*4096);    \
      _Pragma("unroll")                                                        \
      for (int kb = 0; kb < 16; ++kb) WP[kb] = pw_[kb];                        \
      BP = *(const volatile float*)(Br + lp_*64); }                            \
    bpart = __builtin_fmaf(BU, v, bpart);                                      \
    { float a0=0.f, a1=0.f, a2=0.f, a3=0.f;                                    \
      _Pragma("unroll")                                                        \
      for (int kb = 0; kb < 16; ++kb) {                                        \
        f4 vv = *(const f4*)&s_v[kb*4];  /* same-addr broadcast, conflict-free */\
        a0 = __builtin_fmaf(WU[kb].x, vv.x, a0);                               \
        a1 = __builtin_fmaf(WU[kb].y, vv.y, a1);                               \
        a2 = __builtin_fmaf(WU[kb].z, vv.z, a2);                               \
        a3 = __builtin_fmaf(WU[kb].w, vv.w, a3);                               \
      }                                                                        \
      v = (a0 + a1) + (a2 + a3); }                                             \
  } while (0)

  #pragma unroll 1
  for (int i = 63; i >= 3; i -= 4) {       // 16 iterations, layers i..i-3
    CSTEP(w0, b0, w2, b2, i-2);
    CSTEP(w1, b1, w3, b3, i-3);
    CSTEP(w2, b2, w0, b0, i-4);            // i-4 < 0 only in last iter -> clamp
    CSTEP(w3, b3, w1, b1, i-5);
  }
#undef CSTEP
  // v == v_0[lane]; bpart = this lane's share of beta = sum_i bhid[i].v_{i+1}

  // beta_total = sum_k (bpart[k] + bin[k]*v0[k]);  bias row = beta + bout[q]
  float red = __builtin_fmaf(bin[lane], v, bpart);
  #pragma unroll
  for (int off = 32; off > 0; off >>= 1) red += __shfl_xor(red, off, 64);

  s_v[lane] = v;                           // share v0 for the Win fold
  __builtin_amdgcn_sched_barrier(0);

  if (lane == din) {
    weff[din*16 + q] = red + bout[q];
  } else if (lane < din) {
    float a0=0.f, a1=0.f, a2=0.f, a3=0.f;
    const float* wr = Win + (size_t)lane*64;
    #pragma unroll
    for (int kb = 0; kb < 16; ++kb) {
      f4 vv = *(const f4*)&s_v[kb*4];
      f4 wv = *(const f4*)&wr[kb*4];
      a0 = __builtin_fmaf(wv.x, vv.x, a0);
      a1 = __builtin_fmaf(wv.y, vv.y, a1);
      a2 = __builtin_fmaf(wv.z, vv.z, a2);
      a3 = __builtin_fmaf(wv.w, vv.w, a3);
    }
    weff[lane*16 + q] = (a0 + a1) + (a2 + a3);
  }
}

// ---------------------------------------------------------------------------
// apply: blocks [0,79) node rows; rest edge rows. (validated R3/R5, ~2.3 µs)
// ---------------------------------------------------------------------------
template<int NF>
static __device__ __forceinline__ void mlp_apply_store(const float* x, const float* sW,
                                                       float* po)
{
  float a[16];
  #pragma unroll
  for (int q = 0; q < 16; ++q) a[q] = sW[NF*16 + q];   // bias row
  #pragma unroll
  for (int j = 0; j < NF; ++j) {
    const float xv = x[j];
    #pragma unroll
    for (int q = 0; q < 16; ++q) a[q] += xv * sW[j*16 + q];
  }
  float4* d = (float4*)po;
  d[0] = make_float4(a[0],  a[1],  a[2],  a[3]);
  d[1] = make_float4(a[4],  a[5],  a[6],  a[7]);
  d[2] = make_float4(a[8],  a[9],  a[10], a[11]);
  d[3] = make_float4(a[12], a[13], a[14], a[15]);
}

__global__ __launch_bounds__(256) void apply_kernel(
    const float* __restrict__ nodes, const float* __restrict__ globals_,
    const float* __restrict__ edges, const int* __restrict__ senders,
    const int* __restrict__ receivers, const float* __restrict__ ws,
    float* __restrict__ out)
{
  __shared__ float sW[32*16];
  const bool is_node = (blockIdx.x < NODE_BLOCKS);
  {
    const float* src = is_node ? ws : ws + 512;
    const int n = is_node ? 32*16 : 8*16;
    for (int j = threadIdx.x; j < n; j += 256) sW[j] = src[j];
  }
  __syncthreads();

  if (is_node) {
    const int rn = blockIdx.x*256 + threadIdx.x;
    if (rn >= NODE_ROWS) return;
    float x[31];
    const float* p = nodes + (size_t)rn*30;
    #pragma unroll
    for (int j = 0; j < 15; ++j) {
      float2 u = *(const float2*)(p + j*2);
      x[2*j]     = u.x;
      x[2*j + 1] = u.y;
    }
    const int b = (rn >= NN) ? 1 : 0;
    x[30] = globals_[b];
    mlp_apply_store<31>(x, sW, out + (size_t)rn*16);
  } else {
    const int re = (blockIdx.x - NODE_BLOCKS)*256 + threadIdx.x;  // < 160000 exact
    const int b = (re >= EE_) ? 1 : 0;
    float x[7];
    const float* ep = edges + (size_t)re*3;
    x[0] = ep[0]; x[1] = ep[1]; x[2] = ep[2];
    const int si = senders[re], ri = receivers[re];
    const float* ps = nodes + ((size_t)(b*NN + si))*30;
    const float* pr = nodes + ((size_t)(b*NN + ri))*30;
    const float dx = ps[0] - pr[0];
    const float dy = ps[1] - pr[1];
    const float dz = ps[2] - pr[2];
    x[3] = dx; x[4] = dy; x[5] = dz;
    x[6] = sqrtf(dx*dx + dy*dy + dz*dz);
    mlp_apply_store<7>(x, sW, out + (size_t)(NODE_ROWS + re)*16);
  }
}

extern "C" void kernel_launch(void* const* d_in, const int* in_sizes, int n_in,
                              void* d_out, int out_size, void* d_ws, size_t ws_size,
                              hipStream_t stream)
{
  const float* nodes    = (const float*)d_in[0];
  const float* globals_ = (const float*)d_in[1];
  const float* edges    = (const float*)d_in[2];
  const int* senders   = (const int*)d_in[3];
  const int* receivers = (const int*)d_in[4];
  const float* nWin  = (const float*)d_in[5];
  const float* nbin  = (const float*)d_in[6];
  const float* nWhid = (const float*)d_in[7];
  const float* nbhid = (const float*)d_in[8];
  const float* nWout = (const float*)d_in[9];
  const float* nbout = (const float*)d_in[10];
  const float* eWin  = (const float*)d_in[11];
  const float* ebin  = (const float*)d_in[12];
  const float* eWhid = (const float*)d_in[13];
  const float* ebhid = (const float*)d_in[14];
  const float* eWout = (const float*)d_in[15];
  const float* ebout = (const float*)d_in[16];
  float* ws  = (float*)d_ws;
  float* out = (float*)d_out;

  chain_kernel<<<32, 64, 0, stream>>>(
      nWin, nbin, nWhid, nbhid, nWout, nbout,
      eWin, ebin, eWhid, ebhid, eWout, ebout, ws);

  apply_kernel<<<NODE_BLOCKS + EDGE_BLOCKS, 256, 0, stream>>>(
      nodes, globals_, edges, senders, receivers, ws, out);
}

// Round 9
// 67.145 us; speedup vs baseline: 3.0854x; 3.0854x over previous
//
#include <hip/hip_runtime.h>

#define NN 10000
#define EE_ 80000
#define NODE_ROWS 20000
#define NODE_BLOCKS 79         // ceil(20000/256)
#define EDGE_BLOCKS 625        // 160000/256 exact

typedef float f4 __attribute__((ext_vector_type(4)));

// ---------------------------------------------------------------------------
// chain_kernel: 32 blocks x 64 threads (1 wave). Block (c,q) evolves column q
// of chain c's 64x16 suffix product right-to-left:
//   v_64 = Wout[:,q];  v_i = Whid[i] @ v_{i+1};  beta += bhid[i].v_{i+1}
// Per step: 16 independent dwordx4 loads at the TOP, used immediately below
// -> compiler batch-issues them with ONE counted vmcnt (no per-load
// serialization: R5 sank loads to uses, R8's volatile waited per access).
// ws: [0..512) node W_eff 32x16, [512..640) edge 8x16.
// ---------------------------------------------------------------------------
__global__ __launch_bounds__(64, 1) void chain_kernel(
    const float* __restrict__ nWin, const float* __restrict__ nbin,
    const float* __restrict__ nWhid, const float* __restrict__ nbhid,
    const float* __restrict__ nWout, const float* __restrict__ nbout,
    const float* __restrict__ eWin, const float* __restrict__ ebin,
    const float* __restrict__ eWhid, const float* __restrict__ ebhid,
    const float* __restrict__ eWout, const float* __restrict__ ebout,
    float* __restrict__ ws)
{
  const int lane = threadIdx.x;          // 0..63 = vector row k
  const int c = blockIdx.x >> 4;         // 0 node, 1 edge
  const int q = blockIdx.x & 15;         // output column
  const float* Win  = c ? eWin  : nWin;
  const float* bin  = c ? ebin  : nbin;
  const float* Whid = c ? eWhid : nWhid;
  const float* bhid = c ? ebhid : nbhid;
  const float* Wout = c ? eWout : nWout;
  const float* bout = c ? ebout : nbout;
  const int din = c ? 7 : 31;
  float* weff = ws + (c ? 512 : 0);

  __shared__ float s_v[64];

  const float* Wr = Whid + (size_t)lane*64;   // this lane's row base
  const float* Br = bhid + lane;

  float v = Wout[lane*16 + q];                // v_64[lane]
  float bpart = 0.f;

  #pragma unroll 1
  for (int i = 63; i >= 0; --i) {
    // --- batched load: 16 independent dwordx4 + 1 dword, one wait at use ---
    f4 w[16];
    const f4* pw = (const f4*)(Wr + (size_t)i*4096);
    #pragma unroll
    for (int kb = 0; kb < 16; ++kb) w[kb] = pw[kb];
    const float bb = Br[i*64];

    // --- share v, accumulate bias part, GEMV row ---
    s_v[lane] = v;
    bpart = __builtin_fmaf(bb, v, bpart);
    float a0=0.f, a1=0.f, a2=0.f, a3=0.f;
    #pragma unroll
    for (int kb = 0; kb < 16; ++kb) {
      f4 vv = *(const f4*)&s_v[kb*4];     // same-addr broadcast, conflict-free
      a0 = __builtin_fmaf(w[kb].x, vv.x, a0);
      a1 = __builtin_fmaf(w[kb].y, vv.y, a1);
      a2 = __builtin_fmaf(w[kb].z, vv.z, a2);
      a3 = __builtin_fmaf(w[kb].w, vv.w, a3);
    }
    v = (a0 + a1) + (a2 + a3);
  }
  // v == v_0[lane]; bpart = this lane's share of beta = sum_i bhid[i].v_{i+1}

  // beta_total = sum_k (bpart[k] + bin[k]*v0[k]);  bias row = beta + bout[q]
  float red = __builtin_fmaf(bin[lane], v, bpart);
  #pragma unroll
  for (int off = 32; off > 0; off >>= 1) red += __shfl_xor(red, off, 64);

  s_v[lane] = v;                           // share v0 for the Win fold
  __builtin_amdgcn_sched_barrier(0);

  if (lane == din) {
    weff[din*16 + q] = red + bout[q];
  } else if (lane < din) {
    float a0=0.f, a1=0.f, a2=0.f, a3=0.f;
    const float* wr = Win + (size_t)lane*64;
    #pragma unroll
    for (int kb = 0; kb < 16; ++kb) {
      f4 vv = *(const f4*)&s_v[kb*4];
      f4 wv = *(const f4*)&wr[kb*4];
      a0 = __builtin_fmaf(wv.x, vv.x, a0);
      a1 = __builtin_fmaf(wv.y, vv.y, a1);
      a2 = __builtin_fmaf(wv.z, vv.z, a2);
      a3 = __builtin_fmaf(wv.w, vv.w, a3);
    }
    weff[lane*16 + q] = (a0 + a1) + (a2 + a3);
  }
}

// ---------------------------------------------------------------------------
// apply: blocks [0,79) node rows; rest edge rows. (validated R3/R5/R8, ~2.3 µs)
// ---------------------------------------------------------------------------
template<int NF>
static __device__ __forceinline__ void mlp_apply_store(const float* x, const float* sW,
                                                       float* po)
{
  float a[16];
  #pragma unroll
  for (int q = 0; q < 16; ++q) a[q] = sW[NF*16 + q];   // bias row
  #pragma unroll
  for (int j = 0; j < NF; ++j) {
    const float xv = x[j];
    #pragma unroll
    for (int q = 0; q < 16; ++q) a[q] += xv * sW[j*16 + q];
  }
  float4* d = (float4*)po;
  d[0] = make_float4(a[0],  a[1],  a[2],  a[3]);
  d[1] = make_float4(a[4],  a[5],  a[6],  a[7]);
  d[2] = make_float4(a[8],  a[9],  a[10], a[11]);
  d[3] = make_float4(a[12], a[13], a[14], a[15]);
}

__global__ __launch_bounds__(256) void apply_kernel(
    const float* __restrict__ nodes, const float* __restrict__ globals_,
    const float* __restrict__ edges, const int* __restrict__ senders,
    const int* __restrict__ receivers, const float* __restrict__ ws,
    float* __restrict__ out)
{
  __shared__ float sW[32*16];
  const bool is_node = (blockIdx.x < NODE_BLOCKS);
  {
    const float* src = is_node ? ws : ws + 512;
    const int n = is_node ? 32*16 : 8*16;
    for (int j = threadIdx.x; j < n; j += 256) sW[j] = src[j];
  }
  __syncthreads();

  if (is_node) {
    const int rn = blockIdx.x*256 + threadIdx.x;
    if (rn >= NODE_ROWS) return;
    float x[31];
    const float* p = nodes + (size_t)rn*30;
    #pragma unroll
    for (int j = 0; j < 15; ++j) {
      float2 u = *(const float2*)(p + j*2);
      x[2*j]     = u.x;
      x[2*j + 1] = u.y;
    }
    const int b = (rn >= NN) ? 1 : 0;
    x[30] = globals_[b];
    mlp_apply_store<31>(x, sW, out + (size_t)rn*16);
  } else {
    const int re = (blockIdx.x - NODE_BLOCKS)*256 + threadIdx.x;  // < 160000 exact
    const int b = (re >= EE_) ? 1 : 0;
    float x[7];
    const float* ep = edges + (size_t)re*3;
    x[0] = ep[0]; x[1] = ep[1]; x[2] = ep[2];
    const int si = senders[re], ri = receivers[re];
    const float* ps = nodes + ((size_t)(b*NN + si))*30;
    const float* pr = nodes + ((size_t)(b*NN + ri))*30;
    const float dx = ps[0] - pr[0];
    const float dy = ps[1] - pr[1];
    const float dz = ps[2] - pr[2];
    x[3] = dx; x[4] = dy; x[5] = dz;
    x[6] = sqrtf(dx*dx + dy*dy + dz*dz);
    mlp_apply_store<7>(x, sW, out + (size_t)(NODE_ROWS + re)*16);
  }
}

extern "C" void kernel_launch(void* const* d_in, const int* in_sizes, int n_in,
                              void* d_out, int out_size, void* d_ws, size_t ws_size,
                              hipStream_t stream)
{
  const float* nodes    = (const float*)d_in[0];
  const float* globals_ = (const float*)d_in[1];
  const float* edges    = (const float*)d_in[2];
  const int* senders   = (const int*)d_in[3];
  const int* receivers = (const int*)d_in[4];
  const float* nWin  = (const float*)d_in[5];
  const float* nbin  = (const float*)d_in[6];
  const float* nWhid = (const float*)d_in[7];
  const float* nbhid = (const float*)d_in[8];
  const float* nWout = (const float*)d_in[9];
  const float* nbout = (const float*)d_in[10];
  const float* eWin  = (const float*)d_in[11];
  const float* ebin  = (const float*)d_in[12];
  const float* eWhid = (const float*)d_in[13];
  const float* ebhid = (const float*)d_in[14];
  const float* eWout = (const float*)d_in[15];
  const float* ebout = (const float*)d_in[16];
  float* ws  = (float*)d_ws;
  float* out = (float*)d_out;

  chain_kernel<<<32, 64, 0, stream>>>(
      nWin, nbin, nWhid, nbhid, nWout, nbout,
      eWin, ebin, eWhid, ebhid, eWout, ebout, ws);

  apply_kernel<<<NODE_BLOCKS + EDGE_BLOCKS, 256, 0, stream>>>(
      nodes, globals_, edges, senders, receivers, ws, out);
}

// Round 10
// 57.107 us; speedup vs baseline: 3.6278x; 1.1758x over previous
//
#include <hip/hip_runtime.h>

#define NN 10000
#define EE_ 80000
#define NODE_ROWS 20000
#define NODE_BLOCKS 79         // ceil(20000/256)
#define EDGE_BLOCKS 625        // 160000/256 exact

typedef float f4 __attribute__((ext_vector_type(4)));

// async global->LDS staging: side-effecting intrinsic, cannot be sunk (the
// R5/R9 failure) and has no dest VGPR to serialize on (the R8 failure).
#define GLD4(g, l) __builtin_amdgcn_global_load_lds(                      \
    (const __attribute__((address_space(1))) void*)(g),                   \
    (__attribute__((address_space(3))) void*)(l), 16, 0, 0)
#define GLD1(g, l) __builtin_amdgcn_global_load_lds(                      \
    (const __attribute__((address_space(1))) void*)(g),                   \
    (__attribute__((address_space(3))) void*)(l), 4, 0, 0)

// ---------------------------------------------------------------------------
// chain_kernel: 32 blocks x 64 threads (1 wave). Block (c,q) evolves column q
// of chain c's 64x16 suffix product right-to-left:
//   v_64 = Wout[:,q];  v_i = Whid[i] @ v_{i+1};  beta += bhid[i].v_{i+1}
// Weights staged 2 layers ahead into 3 rotating LDS buffers via
// global_load_lds + counted vmcnt(34) (never 0 mid-loop).
// LDS layout XOR-swizzled: LDS[r][granule g] = W[r][g ^ (r&7)] (pre-swizzled
// global source, linear LDS dest, same XOR on read) -> conflict-free b128.
// ws: [0..512) node W_eff 32x16, [512..640) edge 8x16.
// ---------------------------------------------------------------------------
__global__ __launch_bounds__(64, 1) void chain_kernel(
    const float* __restrict__ nWin, const float* __restrict__ nbin,
    const float* __restrict__ nWhid, const float* __restrict__ nbhid,
    const float* __restrict__ nWout, const float* __restrict__ nbout,
    const float* __restrict__ eWin, const float* __restrict__ ebin,
    const float* __restrict__ eWhid, const float* __restrict__ ebhid,
    const float* __restrict__ eWout, const float* __restrict__ ebout,
    float* __restrict__ ws)
{
  const int lane = threadIdx.x;          // 0..63 = vector row k
  const int c = blockIdx.x >> 4;         // 0 node, 1 edge
  const int q = blockIdx.x & 15;         // output column
  const float* Win  = c ? eWin  : nWin;
  const float* bin  = c ? ebin  : nbin;
  const float* Whid = c ? eWhid : nWhid;
  const float* bhid = c ? ebhid : nbhid;
  const float* Wout = c ? eWout : nWout;
  const float* bout = c ? ebout : nbout;
  const int din = c ? 7 : 31;
  float* weff = ws + (c ? 512 : 0);

  __shared__ float lds[3][4160];   // [0..4096) swizzled W, [4096..4160) bias
  __shared__ float s_v[64];

  // stage-side address math: issue j, lane l writes LDS row r = j*4 + (l>>4),
  // granule c16 = l&15. Source must be W[r][c16 ^ (r&7)];
  // r&7 = ((j&1)<<2) | (l>>4)  ->  two per-lane offsets by j parity.
  const int r4  = lane >> 4;
  const int c16 = lane & 15;
  const int oE = r4*64 + ((c16 ^ r4) << 2);        // j even
  const int oO = r4*64 + ((c16 ^ (4 | r4)) << 2);  // j odd
  const int swz = lane & 7;                        // read-side XOR (row = lane)

  float v = Wout[lane*16 + q];                     // v_64[lane]
  float bpart = 0.f;

#define STAGE(B, L) do {                                                  \
    const float* gb_ = Whid + (size_t)(L)*4096;                           \
    _Pragma("unroll")                                                     \
    for (int j = 0; j < 16; ++j)                                          \
      GLD4(gb_ + j*256 + ((j & 1) ? oO : oE), &lds[B][j*256]);            \
    GLD1(bhid + (L)*64 + lane, &lds[B][4096]);                            \
  } while (0)

  // one chain step on buffer B (layer value lives in the staging schedule)
#define CSTEP(B, STMT, VMC) do {                                          \
    STMT;                                                                 \
    asm volatile("s_waitcnt vmcnt(" #VMC ")" ::: "memory");               \
    __builtin_amdgcn_sched_barrier(0);                                    \
    float bb_ = lds[B][4096 + lane];                                      \
    f4 w_[16];                                                            \
    _Pragma("unroll")                                                     \
    for (int kb = 0; kb < 16; ++kb)                                       \
      w_[kb] = *(const f4*)&lds[B][lane*64 + ((kb ^ swz) << 2)];          \
    s_v[lane] = v;                                                        \
    bpart = __builtin_fmaf(bb_, v, bpart);                                \
    float a0=0.f, a1=0.f, a2=0.f, a3=0.f;                                 \
    _Pragma("unroll")                                                     \
    for (int kb = 0; kb < 16; ++kb) {                                     \
      f4 vv = *(const f4*)&s_v[kb*4];   /* same-addr broadcast */         \
      a0 = __builtin_fmaf(w_[kb].x, vv.x, a0);                            \
      a1 = __builtin_fmaf(w_[kb].y, vv.y, a1);                            \
      a2 = __builtin_fmaf(w_[kb].z, vv.z, a2);                            \
      a3 = __builtin_fmaf(w_[kb].w, vv.w, a3);                            \
    }                                                                     \
    v = (a0 + a1) + (a2 + a3);                                            \
  } while (0)

  // prologue: prime layers 63 (buf0) and 62 (buf1)
  STAGE(0, 63);
  STAGE(1, 62);

  // main: layers 63..4, 20 iterations x 3 steps; buffer (63-L)%3
  int L = 63;
  #pragma unroll 1
  for (int ii = 0; ii < 20; ++ii) {
    CSTEP(0, STAGE(2, L-2), 34);
    CSTEP(1, STAGE(0, L-3), 34);
    CSTEP(2, STAGE(1, L-4), 34);
    L -= 3;
  }
  // epilogue: layers 3,2,1,0 (stages for 1 and 0; then drain)
  CSTEP(0, STAGE(2, 1), 34);
  CSTEP(1, STAGE(0, 0), 34);
  CSTEP(2, ((void)0), 17);
  CSTEP(0, ((void)0), 0);
#undef CSTEP
#undef STAGE
  // v == v_0[lane]; bpart = this lane's share of beta = sum_i bhid[i].v_{i+1}

  // beta_total = sum_k (bpart[k] + bin[k]*v0[k]);  bias row = beta + bout[q]
  float red = __builtin_fmaf(bin[lane], v, bpart);
  #pragma unroll
  for (int off = 32; off > 0; off >>= 1) red += __shfl_xor(red, off, 64);

  s_v[lane] = v;                           // share v0 for the Win fold
  __builtin_amdgcn_sched_barrier(0);

  if (lane == din) {
    weff[din*16 + q] = red + bout[q];
  } else if (lane < din) {
    float a0=0.f, a1=0.f, a2=0.f, a3=0.f;
    const float* wr = Win + (size_t)lane*64;
    #pragma unroll
    for (int kb = 0; kb < 16; ++kb) {
      f4 vv = *(const f4*)&s_v[kb*4];
      f4 wv = *(const f4*)&wr[kb*4];
      a0 = __builtin_fmaf(wv.x, vv.x, a0);
      a1 = __builtin_fmaf(wv.y, vv.y, a1);
      a2 = __builtin_fmaf(wv.z, vv.z, a2);
      a3 = __builtin_fmaf(wv.w, vv.w, a3);
    }
    weff[lane*16 + q] = (a0 + a1) + (a2 + a3);
  }
}

// ---------------------------------------------------------------------------
// apply: blocks [0,79) node rows; rest edge rows. (validated R3/R5/R8/R9)
// ---------------------------------------------------------------------------
template<int NF>
static __device__ __forceinline__ void mlp_apply_store(const float* x, const float* sW,
                                                       float* po)
{
  float a[16];
  #pragma unroll
  for (int q = 0; q < 16; ++q) a[q] = sW[NF*16 + q];   // bias row
  #pragma unroll
  for (int j = 0; j < NF; ++j) {
    const float xv = x[j];
    #pragma unroll
    for (int q = 0; q < 16; ++q) a[q] += xv * sW[j*16 + q];
  }
  float4* d = (float4*)po;
  d[0] = make_float4(a[0],  a[1],  a[2],  a[3]);
  d[1] = make_float4(a[4],  a[5],  a[6],  a[7]);
  d[2] = make_float4(a[8],  a[9],  a[10], a[11]);
  d[3] = make_float4(a[12], a[13], a[14], a[15]);
}

__global__ __launch_bounds__(256) void apply_kernel(
    const float* __restrict__ nodes, const float* __restrict__ globals_,
    const float* __restrict__ edges, const int* __restrict__ senders,
    const int* __restrict__ receivers, const float* __restrict__ ws,
    float* __restrict__ out)
{
  __shared__ float sW[32*16];
  const bool is_node = (blockIdx.x < NODE_BLOCKS);
  {
    const float* src = is_node ? ws : ws + 512;
    const int n = is_node ? 32*16 : 8*16;
    for (int j = threadIdx.x; j < n; j += 256) sW[j] = src[j];
  }
  __syncthreads();

  if (is_node) {
    const int rn = blockIdx.x*256 + threadIdx.x;
    if (rn >= NODE_ROWS) return;
    float x[31];
    const float* p = nodes + (size_t)rn*30;
    #pragma unroll
    for (int j = 0; j < 15; ++j) {
      float2 u = *(const float2*)(p + j*2);
      x[2*j]     = u.x;
      x[2*j + 1] = u.y;
    }
    const int b = (rn >= NN) ? 1 : 0;
    x[30] = globals_[b];
    mlp_apply_store<31>(x, sW, out + (size_t)rn*16);
  } else {
    const int re = (blockIdx.x - NODE_BLOCKS)*256 + threadIdx.x;  // < 160000 exact
    const int b = (re >= EE_) ? 1 : 0;
    float x[7];
    const float* ep = edges + (size_t)re*3;
    x[0] = ep[0]; x[1] = ep[1]; x[2] = ep[2];
    const int si = senders[re], ri = receivers[re];
    const float* ps = nodes + ((size_t)(b*NN + si))*30;
    const float* pr = nodes + ((size_t)(b*NN + ri))*30;
    const float dx = ps[0] - pr[0];
    const float dy = ps[1] - pr[1];
    const float dz = ps[2] - pr[2];
    x[3] = dx; x[4] = dy; x[5] = dz;
    x[6] = sqrtf(dx*dx + dy*dy + dz*dz);
    mlp_apply_store<7>(x, sW, out + (size_t)(NODE_ROWS + re)*16);
  }
}

extern "C" void kernel_launch(void* const* d_in, const int* in_sizes, int n_in,
                              void* d_out, int out_size, void* d_ws, size_t ws_size,
                              hipStream_t stream)
{
  const float* nodes    = (const float*)d_in[0];
  const float* globals_ = (const float*)d_in[1];
  const float* edges    = (const float*)d_in[2];
  const int* senders   = (const int*)d_in[3];
  const int* receivers = (const int*)d_in[4];
  const float* nWin  = (const float*)d_in[5];
  const float* nbin  = (const float*)d_in[6];
  const float* nWhid = (const float*)d_in[7];
  const float* nbhid = (const float*)d_in[8];
  const float* nWout = (const float*)d_in[9];
  const float* nbout = (const float*)d_in[10];
  const float* eWin  = (const float*)d_in[11];
  const float* ebin  = (const float*)d_in[12];
  const float* eWhid = (const float*)d_in[13];
  const float* ebhid = (const float*)d_in[14];
  const float* eWout = (const float*)d_in[15];
  const float* ebout = (const float*)d_in[16];
  float* ws  = (float*)d_ws;
  float* out = (float*)d_out;

  chain_kernel<<<32, 64, 0, stream>>>(
      nWin, nbin, nWhid, nbhid, nWout, nbout,
      eWin, ebin, eWhid, ebhid, eWout, ebout, ws);

  apply_kernel<<<NODE_BLOCKS + EDGE_BLOCKS, 256, 0, stream>>>(
      nodes, globals_, edges, senders, receivers, ws, out);
}

// Round 11
// 45.410 us; speedup vs baseline: 4.5622x; 1.2576x over previous
//
#include <hip/hip_runtime.h>

#define NN 10000
#define EE_ 80000
#define NODE_ROWS 20000
#define NODE_BLOCKS 79         // ceil(20000/256)
#define EDGE_BLOCKS 625        // 160000/256 exact

typedef float f4 __attribute__((ext_vector_type(4)));

#define GLD4(g, l) __builtin_amdgcn_global_load_lds(                      \
    (const __attribute__((address_space(1))) void*)(g),                   \
    (__attribute__((address_space(3))) void*)(l), 16, 0, 0)
#define GLD1(g, l) __builtin_amdgcn_global_load_lds(                      \
    (const __attribute__((address_space(1))) void*)(g),                   \
    (__attribute__((address_space(3))) void*)(l), 4, 0, 0)

// ---------------------------------------------------------------------------
// chain_kernel: 32 blocks x 256 threads (4 waves). Block (c,q): column q of
// chain c's 64x16 suffix product. Wave w owns k-slice [16w,16w+16):
//   partial_w[lane] = sum_{k in slice} W[lane][k] * v[k]
//   v'[lane] = sum_w partial_w[lane]   (LDS s_p exchange, 2 raw barriers/step)
// v[k] scalars live in SGPRs via readlane (no LDS broadcast). W staged
// 2-deep into 3 LDS buffers via global_load_lds, counted vmcnt(10).
// ALL ds ops are inline-asm (compiler-invisible; no hidden vmcnt(0) drains).
// LDS: 3 x 4352 f (4096 swizzled W + 64 bias + 192 dummy) + 256 f partials.
// ws: [0..512) node W_eff 32x16, [512..640) edge 8x16.
// ---------------------------------------------------------------------------
__global__ __launch_bounds__(256, 1) void chain_kernel(
    const float* __restrict__ nWin, const float* __restrict__ nbin,
    const float* __restrict__ nWhid, const float* __restrict__ nbhid,
    const float* __restrict__ nWout, const float* __restrict__ nbout,
    const float* __restrict__ eWin, const float* __restrict__ ebin,
    const float* __restrict__ eWhid, const float* __restrict__ ebhid,
    const float* __restrict__ eWout, const float* __restrict__ ebout,
    float* __restrict__ ws)
{
  const int tid  = threadIdx.x;
  const int lane = tid & 63;
  const int wv   = __builtin_amdgcn_readfirstlane(tid >> 6);  // 0..3
  const int c = blockIdx.x >> 4;         // 0 node, 1 edge
  const int q = blockIdx.x & 15;         // output column
  const float* Win  = c ? eWin  : nWin;
  const float* bin  = c ? ebin  : nbin;
  const float* Whid = c ? eWhid : nWhid;
  const float* bhid = c ? ebhid : nbhid;
  const float* Wout = c ? eWout : nWout;
  const float* bout = c ? ebout : nbout;
  const int din = c ? 7 : 31;
  float* weff = ws + (c ? 512 : 0);

  __shared__ float lds_f[13312];   // 3*4352 buffers + 256 partials = 53 KB

  // stage-side pre-swizzle offsets (R10-verified): lds[r][g] = W[r][g^(r&7)]
  const int r4 = lane >> 4, c16 = lane & 15;
  const int oE = r4*64 + ((c16 ^ r4) << 2);        // GLD4 slot parity even
  const int oO = r4*64 + ((c16 ^ (4 | r4)) << 2);  // GLD4 slot parity odd
  // read-side byte addresses (per-step invariant; buffer chosen via offset:)
  const int swz = lane & 7;
  const int aw0 = lane*256 + (((4*wv + 0) ^ swz) << 4);
  const int aw1 = lane*256 + (((4*wv + 1) ^ swz) << 4);
  const int aw2 = lane*256 + (((4*wv + 2) ^ swz) << 4);
  const int aw3 = lane*256 + (((4*wv + 3) ^ swz) << 4);
  const int ab  = 16384 + wv*256 + lane*4;          // bias copy (per-wave)
  const int apw = 52224 + lane*16 + wv*4;           // partial write
  const int apr = 52224 + lane*16;                  // partial read (b128)

  float vlane = Wout[lane*16 + q];                  // v_64[lane]
  float bpart = 0.f;
  const int kbase = 16*wv;
  float s[16];
  #pragma unroll
  for (int j = 0; j < 16; ++j)
    s[j] = __uint_as_float(__builtin_amdgcn_readlane(__float_as_uint(vlane), kbase + j));

#define STAGE(BF, L) do {                                                 \
    const float* gW_ = Whid + (size_t)(L)*4096 + wv*1024;                 \
    float* lW_ = lds_f + (BF)*4352 + wv*1024;                             \
    GLD4(gW_ +   0 + oE, lW_ +   0);                                      \
    GLD4(gW_ + 256 + oO, lW_ + 256);                                      \
    GLD4(gW_ + 512 + oE, lW_ + 512);                                      \
    GLD4(gW_ + 768 + oO, lW_ + 768);                                      \
    GLD1(bhid + (size_t)(L)*64 + lane, lds_f + (BF)*4352 + 4096 + wv*64); \
  } while (0)

#define CSTEP(OFS, VMC, STAGESTMT) do {                                   \
    STAGESTMT;                                                            \
    asm volatile("s_waitcnt vmcnt(" #VMC ") lgkmcnt(0)" ::: "memory");    \
    __builtin_amdgcn_s_barrier();        /* this step's buffer ready */   \
    f4 f0_, f1_, f2_, f3_; float bb_;                                     \
    asm volatile("ds_read_b128 %0, %5 offset:" #OFS "\n\t"                \
                 "ds_read_b128 %1, %6 offset:" #OFS "\n\t"                \
                 "ds_read_b128 %2, %7 offset:" #OFS "\n\t"                \
                 "ds_read_b128 %3, %8 offset:" #OFS "\n\t"                \
                 "ds_read_b32  %4, %9 offset:" #OFS "\n\t"                \
                 "s_waitcnt lgkmcnt(0)"                                   \
                 : "=&v"(f0_), "=&v"(f1_), "=&v"(f2_), "=&v"(f3_), "=&v"(bb_) \
                 : "v"(aw0), "v"(aw1), "v"(aw2), "v"(aw3), "v"(ab)        \
                 : "memory");                                             \
    __builtin_amdgcn_sched_barrier(0);                                    \
    bpart = __builtin_fmaf(bb_, vlane, bpart);                            \
    float a0_ = __builtin_fmaf(f0_.y, s[1],  f0_.x * s[0]);               \
    a0_ = __builtin_fmaf(f0_.z, s[2],  a0_);                              \
    a0_ = __builtin_fmaf(f0_.w, s[3],  a0_);                              \
    float a1_ = __builtin_fmaf(f1_.y, s[5],  f1_.x * s[4]);               \
    a1_ = __builtin_fmaf(f1_.z, s[6],  a1_);                              \
    a1_ = __builtin_fmaf(f1_.w, s[7],  a1_);                              \
    float a2_ = __builtin_fmaf(f2_.y, s[9],  f2_.x * s[8]);               \
    a2_ = __builtin_fmaf(f2_.z, s[10], a2_);                              \
    a2_ = __builtin_fmaf(f2_.w, s[11], a2_);                              \
    float a3_ = __builtin_fmaf(f3_.y, s[13], f3_.x * s[12]);              \
    a3_ = __builtin_fmaf(f3_.z, s[14], a3_);                              \
    a3_ = __builtin_fmaf(f3_.w, s[15], a3_);                              \
    float acc_ = (a0_ + a1_) + (a2_ + a3_);                               \
    asm volatile("ds_write_b32 %0, %1\n\t"                                \
                 "s_waitcnt lgkmcnt(0)"                                   \
                 :: "v"(apw), "v"(acc_) : "memory");                      \
    __builtin_amdgcn_s_barrier();        /* partials visible */           \
    f4 p4_;                                                               \
    asm volatile("ds_read_b128 %0, %1\n\t"                                \
                 "s_waitcnt lgkmcnt(0)"                                   \
                 : "=&v"(p4_) : "v"(apr) : "memory");                     \
    __builtin_amdgcn_sched_barrier(0);                                    \
    vlane = (p4_.x + p4_.y) + (p4_.z + p4_.w);                            \
    _Pragma("unroll")                                                     \
    for (int jj = 0; jj < 16; ++jj)                                       \
      s[jj] = __uint_as_float(__builtin_amdgcn_readlane(                  \
                  __float_as_uint(vlane), kbase + jj));                   \
  } while (0)

  // prologue: prime buffers 0 (layer 63) and 1 (layer 62) -> 10 outstanding
  STAGE(0, 63);
  STAGE(1, 62);

  int L = 63;
  #pragma unroll 1
  for (int ii = 0; ii < 20; ++ii) {      // layers 63..4
    CSTEP(0,     10, STAGE(2, L-2));
    CSTEP(17408, 10, STAGE(0, L-3));
    CSTEP(34816, 10, STAGE(1, L-4));
    L -= 3;
  }
  // tail: layers 3,2,1,0
  CSTEP(0,     10, STAGE(2, 1));
  CSTEP(17408, 10, STAGE(0, 0));
  CSTEP(34816, 5,  (void)0);
  CSTEP(0,     0,  (void)0);
#undef CSTEP
#undef STAGE
  // vlane == v_0[lane]; bpart = lane's share of beta (identical in all waves)

  if (wv != 0) return;                   // no barriers below

  // beta_total = sum_k (bpart[k] + bin[k]*v0[k]);  bias row = beta + bout[q]
  float red = __builtin_fmaf(bin[lane], vlane, bpart);
  #pragma unroll
  for (int off = 32; off > 0; off >>= 1) red += __shfl_xor(red, off, 64);

  float* sv = lds_f;                     // buffers dead; share v0 wave-locally
  sv[lane] = vlane;
  __builtin_amdgcn_sched_barrier(0);

  if (lane == din) {
    weff[din*16 + q] = red + bout[q];
  } else if (lane < din) {
    float a0 = 0.f, a1 = 0.f, a2 = 0.f, a3 = 0.f;
    const float* wr = Win + (size_t)lane*64;
    #pragma unroll
    for (int kb = 0; kb < 16; ++kb) {
      f4 vv = *(const f4*)&sv[kb*4];
      f4 wv4 = *(const f4*)&wr[kb*4];
      a0 = __builtin_fmaf(wv4.x, vv.x, a0);
      a1 = __builtin_fmaf(wv4.y, vv.y, a1);
      a2 = __builtin_fmaf(wv4.z, vv.z, a2);
      a3 = __builtin_fmaf(wv4.w, vv.w, a3);
    }
    weff[lane*16 + q] = (a0 + a1) + (a2 + a3);
  }
}

// ---------------------------------------------------------------------------
// apply: blocks [0,79) node rows; rest edge rows. (validated R3..R10, ~2.3 µs)
// ---------------------------------------------------------------------------
template<int NF>
static __device__ __forceinline__ void mlp_apply_store(const float* x, const float* sW,
                                                       float* po)
{
  float a[16];
  #pragma unroll
  for (int q = 0; q < 16; ++q) a[q] = sW[NF*16 + q];   // bias row
  #pragma unroll
  for (int j = 0; j < NF; ++j) {
    const float xv = x[j];
    #pragma unroll
    for (int q = 0; q < 16; ++q) a[q] += xv * sW[j*16 + q];
  }
  float4* d = (float4*)po;
  d[0] = make_float4(a[0],  a[1],  a[2],  a[3]);
  d[1] = make_float4(a[4],  a[5],  a[6],  a[7]);
  d[2] = make_float4(a[8],  a[9],  a[10], a[11]);
  d[3] = make_float4(a[12], a[13], a[14], a[15]);
}

__global__ __launch_bounds__(256) void apply_kernel(
    const float* __restrict__ nodes, const float* __restrict__ globals_,
    const float* __restrict__ edges, const int* __restrict__ senders,
    const int* __restrict__ receivers, const float* __restrict__ ws,
    float* __restrict__ out)
{
  __shared__ float sW[32*16];
  const bool is_node = (blockIdx.x < NODE_BLOCKS);
  {
    const float* src = is_node ? ws : ws + 512;
    const int n = is_node ? 32*16 : 8*16;
    for (int j = threadIdx.x; j < n; j += 256) sW[j] = src[j];
  }
  __syncthreads();

  if (is_node) {
    const int rn = blockIdx.x*256 + threadIdx.x;
    if (rn >= NODE_ROWS) return;
    float x[31];
    const float* p = nodes + (size_t)rn*30;
    #pragma unroll
    for (int j = 0; j < 15; ++j) {
      float2 u = *(const float2*)(p + j*2);
      x[2*j]     = u.x;
      x[2*j + 1] = u.y;
    }
    const int b = (rn >= NN) ? 1 : 0;
    x[30] = globals_[b];
    mlp_apply_store<31>(x, sW, out + (size_t)rn*16);
  } else {
    const int re = (blockIdx.x - NODE_BLOCKS)*256 + threadIdx.x;  // < 160000 exact
    const int b = (re >= EE_) ? 1 : 0;
    float x[7];
    const float* ep = edges + (size_t)re*3;
    x[0] = ep[0]; x[1] = ep[1]; x[2] = ep[2];
    const int si = senders[re], ri = receivers[re];
    const float* ps = nodes + ((size_t)(b*NN + si))*30;
    const float* pr = nodes + ((size_t)(b*NN + ri))*30;
    const float dx = ps[0] - pr[0];
    const float dy = ps[1] - pr[1];
    const float dz = ps[2] - pr[2];
    x[3] = dx; x[4] = dy; x[5] = dz;
    x[6] = sqrtf(dx*dx + dy*dy + dz*dz);
    mlp_apply_store<7>(x, sW, out + (size_t)(NODE_ROWS + re)*16);
  }
}

extern "C" void kernel_launch(void* const* d_in, const int* in_sizes, int n_in,
                              void* d_out, int out_size, void* d_ws, size_t ws_size,
                              hipStream_t stream)
{
  const float* nodes    = (const float*)d_in[0];
  const float* globals_ = (const float*)d_in[1];
  const float* edges    = (const float*)d_in[2];
  const int* senders   = (const int*)d_in[3];
  const int* receivers = (const int*)d_in[4];
  const float* nWin  = (const float*)d_in[5];
  const float* nbin  = (const float*)d_in[6];
  const float* nWhid = (const float*)d_in[7];
  const float* nbhid = (const float*)d_in[8];
  const float* nWout = (const float*)d_in[9];
  const float* nbout = (const float*)d_in[10];
  const float* eWin  = (const float*)d_in[11];
  const float* ebin  = (const float*)d_in[12];
  const float* eWhid = (const float*)d_in[13];
  const float* ebhid = (const float*)d_in[14];
  const float* eWout = (const float*)d_in[15];
  const float* ebout = (const float*)d_in[16];
  float* ws  = (float*)d_ws;
  float* out = (float*)d_out;

  chain_kernel<<<32, 256, 0, stream>>>(
      nWin, nbin, nWhid, nbhid, nWout, nbout,
      eWin, ebin, eWhid, ebhid, eWout, ebout, ws);

  apply_kernel<<<NODE_BLOCKS + EDGE_BLOCKS, 256, 0, stream>>>(
      nodes, globals_, edges, senders, receivers, ws, out);
}